// Round 9
// baseline (251.988 us; speedup 1.0000x reference)
//
#include <hip/hip_runtime.h>
#include <hip/hip_bf16.h>

// GCN: h1 = relu(Â (x W1) + b1); h2 = relu(Â (h1 W2) + b2);
// out = mean_pool(h2, batch) @ Wlin + blin,  Â = D^-1/2 (A+I) D^-1/2
//
// R5/R6: bucketed CSR build, deterministic two-pass, zero global atomics.
// R8/R9 LESSON: sub-dword / strided per-lane global stores+atomics defeat
//     L2 write-merge. R12: multi-node unroll spills. R14: atomic chains.
// R15/R16: replicated pooled accumulators (chunk=4, 32 replicas).
// R17: 16-edge tier, 8 row-gathers in flight per half-wave. 280 us.
// R18 LESSON: branchy tails -> path-dependent vmcnt -> drain stalls;
//     strided scalar atomics -> 4x WRITE_SIZE. (Width was NOT the bug.)
// R19: CSR padded to 16-slot tiers (self-loop slot, zero-row pads). 276.6.
// R20: rotated-prefetch gather STREAM across node boundaries. -30 us.
// R20 LESSON: tiny-grid kernels must never own bulk reductions (110 us).
// R21: separate reduce_k + cheap final_k. 250.8 us.
// R22 LESSON: _ord-0 cold dispatch misread; neutral.
// R23 LESSON: depth-2 REGRESSED; CU load queue (entries) saturated.
// R24: agglin_k fusion (agg L1 + gemm L2 via padded LDS tile). 247.7 us.
// R25: csr = byte offsets -> 1-add addressing. 244.2 us. agglin still
//     ~50% VALUBusy: per-tier 8 loads + 8 csr + 32 unpack is the budget.
// R26: dwordx2 gather INSIDE the proven stream skeleton. Lane=(q,r):
//     16 lanes x 8B = full row, q = 4 edges/instr. Per tier: 4 uint2 +
//     4 csr loads (halved), unpack unchanged. Node fold = 8 shfl; lane
//     selects s[q] for dim d=4r+q -> epilogues stay one scalar/lane,
//     contiguous 0..63 (no strided atomics).

#define NDIM 64
#define NGRAPH 64
#define NREP 32
#define BSHIFT 7                      // 128 nodes per bucket
#define BNODES 128
#define PADSLOT (BNODES * 16)         // worst-case extra csr slots per bucket
#define ECHUNK 2048                   // edges per block in bincnt/bscatter
#define EPB (ECHUNK / 256)            // edges per thread (8)

#define BLO(u) __uint_as_float((u) << 16)
#define BHI(u) __uint_as_float((u) & 0xFFFF0000u)

__device__ __forceinline__ unsigned short f32_to_bf16(float f) {
    unsigned int u = __float_as_uint(f);
    unsigned int r = 0x7FFFu + ((u >> 16) & 1u);   // round-to-nearest-even
    return (unsigned short)((u + r) >> 16);
}

// ---- pass 1: per-(block,bucket) edge counts via LDS histogram ----
__global__ void bincnt_k(const int* __restrict__ dst, int* __restrict__ cntmat,
                         int e, int nb) {
    extern __shared__ int hist[];
    int t = threadIdx.x;
    for (int i = t; i < nb; i += 256) hist[i] = 0;
    __syncthreads();
    int base = blockIdx.x * ECHUNK + t;
#pragma unroll
    for (int k = 0; k < EPB; ++k) {
        int i = base + k * 256;
        if (i < e) atomicAdd(&hist[dst[i] >> BSHIFT], 1);   // LDS atomic
    }
    __syncthreads();
    long row = (long)blockIdx.x * nb;
    for (int i = t; i < nb; i += 256) cntmat[row + i] = hist[i];
}

// ---- pass 2: per-bucket exclusive scan across blocks (one block per bucket) ----
// 1024-thread scan (nblk up to 1024). Also zeroes pooledR.
__global__ void colscan_k(const int* __restrict__ cntmat, int* __restrict__ basemat,
                          int* __restrict__ bucketTot, float* __restrict__ pooledR,
                          int nblk, int nb) {
    __shared__ int s[1024];
    int b = blockIdx.x;
    int t = threadIdx.x;
    int z = b * 1024 + t;
    if (z < NREP * NGRAPH * NDIM) pooledR[z] = 0.f;
    int v = (t < nblk) ? cntmat[(long)t * nb + b] : 0;
    s[t] = v;
    __syncthreads();
    for (int off = 1; off < 1024; off <<= 1) {
        int tmp = (t >= off) ? s[t - off] : 0;
        __syncthreads();
        s[t] += tmp;
        __syncthreads();
    }
    if (t < nblk) basemat[(long)t * nb + b] = s[t] - v;   // exclusive within column
    if (t == 1023) bucketTot[b] = s[1023];
}

// ---- pass 3: exclusive scan of bucket totals (single block, nb<=1024) ----
// Also zeroes gstart/gend (empty-graph safety; fill2_k overwrites).
__global__ void bscan_k(const int* __restrict__ bucketTot, int* __restrict__ bucketStart,
                        int* __restrict__ start, int* __restrict__ gstart,
                        int* __restrict__ gend, int nb, int n, int e) {
    __shared__ int s[1024];
    int t = threadIdx.x;
    if (t < NGRAPH) { gstart[t] = 0; gend[t] = 0; }
    int v = (t < nb) ? bucketTot[t] : 0;
    s[t] = v;
    __syncthreads();
    for (int off = 1; off < 1024; off <<= 1) {
        int tmp = (t >= off) ? s[t - off] : 0;
        __syncthreads();
        s[t] += tmp;
        __syncthreads();
    }
    if (t < nb) bucketStart[t + 1] = s[t];
    if (t == 0) { bucketStart[0] = 0; start[n] = e; }   // sentinel (unused by gather)
}

// ---- pass 4: scatter packed (dst_local<<25 | src) via block-private LDS cursors ----
__global__ void bscatter_k(const int* __restrict__ src, const int* __restrict__ dst,
                           const int* __restrict__ bucketStart,
                           const int* __restrict__ basemat,
                           unsigned int* __restrict__ ebuf, int e, int nb) {
    extern __shared__ int cur[];
    int t = threadIdx.x;
    long row = (long)blockIdx.x * nb;
    for (int i = t; i < nb; i += 256) cur[i] = bucketStart[i] + basemat[row + i];
    __syncthreads();
    int base = blockIdx.x * ECHUNK + t;
#pragma unroll
    for (int k = 0; k < EPB; ++k) {
        int i = base + k * 256;
        if (i < e) {
            int d = dst[i];
            int b = d >> BSHIFT;
            int pos = atomicAdd(&cur[b], 1);               // LDS atomic, block-private
            ebuf[pos] = ((unsigned)(d & (BNODES - 1)) << 25) | (unsigned)src[i];
        }
    }
}

// ---- pass 5: one block per bucket -> padded dst-ordered CSR slice, dinv, ranges ----
// Per-node slots = round_up(in_deg + 1(self), 16); bucket b's padded region
// starts at bucketStart[b] + b*PADSLOT. Pad slots point at zero row N.
// csr entries are BYTE offsets (src_id << 7) into the bf16 row table (R25).
__global__ void fill2_k(const unsigned int* __restrict__ ebuf,
                        const int* __restrict__ bucketStart,
                        const int* __restrict__ batch, float* __restrict__ dinv,
                        int* __restrict__ start, int* __restrict__ m16,
                        int* __restrict__ csr,
                        int* __restrict__ gstart, int* __restrict__ gend, int n) {
    __shared__ int scnt[BNODES], sincl[BNODES], scur[BNODES];
    int t = threadIdx.x;
    int b = blockIdx.x;
    int node0 = b << BSHIFT;
    int nNodes = min(BNODES, n - node0);
    if (t < BNODES) scnt[t] = 0;
    int e0 = bucketStart[b], e1 = bucketStart[b + 1];
    __syncthreads();
    for (int i = e0 + t; i < e1; i += 256)
        atomicAdd(&scnt[ebuf[i] >> 25], 1);
    __syncthreads();
    int val = (t < BNODES) ? scnt[t] : 0;
    int slots = (t < nNodes) ? ((val + 16) & ~15) : 0;   // real + self, padded to 16
    if (t < BNODES) sincl[t] = slots;
    __syncthreads();
    for (int off = 1; off < BNODES; off <<= 1) {
        int tmp = (t >= off && t < BNODES) ? sincl[t - off] : 0;
        __syncthreads();
        if (t < BNODES) sincl[t] += tmp;
        __syncthreads();
    }
    if (t < nNodes) {
        int v = node0 + t;
        int st = e0 + b * PADSLOT + sincl[t] - slots;   // exclusive scan, padded base
        start[v] = st;
        m16[v] = slots >> 4;                            // 16-edge tiers per node
        scur[t] = st;
        dinv[v] = rsqrtf((float)(val + 1));
        csr[st + val] = v << 7;                         // self-loop slot (byte off)
        for (int k2 = val + 1; k2 < slots; ++k2) csr[st + k2] = n << 7;  // zero-row pads
        int g = batch[v];                 // sorted-batch boundary detection
        if (v == 0 || batch[v - 1] != g) gstart[g] = v;
        if (v == n - 1 || batch[v + 1] != g) gend[g] = v + 1;
    }
    __syncthreads();
    for (int i = e0 + t; i < e1; i += 256) {
        unsigned rec = ebuf[i];
        int pos = atomicAdd(&scur[rec >> 25], 1);
        csr[pos] = (int)((rec & 0x1FFFFFFu) << 7);   // byte offset of src row
    }
}

// ---- dense GEMM v4  C[n,64](bf16 pairs) = scale[row] * (A[n,64] @ W[64,64]) ----
// Block 0 also zeroes dummy row N (replaces a memset dispatch).
__global__ void gemm_k(const float* __restrict__ A, const float* __restrict__ W,
                       const float* __restrict__ scale,
                       unsigned long long* __restrict__ C, int n) {
    __shared__ float4 Wl4[64 * 16];   // 16 KB: W[k][4c..4c+3]
    __shared__ float4 Xl4[64 * 16];   // 16 KB: X[r][4k..4k+3]
    int t = threadIdx.x;
    if (blockIdx.x == 0 && t < 16) C[(long)n * 16 + t] = 0ULL;   // zero row N
    const float4* W4 = (const float4*)W;
#pragma unroll
    for (int i = 0; i < 4; ++i) Wl4[t + 256 * i] = W4[t + 256 * i];
    const float4* A4 = (const float4*)A;
    long fbase = (long)blockIdx.x * 1024;
    long fmax  = (long)n * 16;
#pragma unroll
    for (int i = 0; i < 4; ++i) {
        long f = fbase + t + 256 * i;
        float4 v;
        if (f < fmax) v = A4[f];
        else { v.x = 0.f; v.y = 0.f; v.z = 0.f; v.w = 0.f; }
        Xl4[t + 256 * i] = v;
    }
    __syncthreads();
    int rg = t >> 4, cg = t & 15;
    float a00 = 0.f, a01 = 0.f, a02 = 0.f, a03 = 0.f;
    float a10 = 0.f, a11 = 0.f, a12 = 0.f, a13 = 0.f;
    float a20 = 0.f, a21 = 0.f, a22 = 0.f, a23 = 0.f;
    float a30 = 0.f, a31 = 0.f, a32 = 0.f, a33 = 0.f;
#pragma unroll 4
    for (int k4 = 0; k4 < 16; ++k4) {
        float4 w0 = Wl4[(4 * k4 + 0) * 16 + cg];
        float4 w1 = Wl4[(4 * k4 + 1) * 16 + cg];
        float4 w2 = Wl4[(4 * k4 + 2) * 16 + cg];
        float4 w3 = Wl4[(4 * k4 + 3) * 16 + cg];
        float4 x0 = Xl4[(4 * rg + 0) * 16 + k4];
        float4 x1 = Xl4[(4 * rg + 1) * 16 + k4];
        float4 x2 = Xl4[(4 * rg + 2) * 16 + k4];
        float4 x3 = Xl4[(4 * rg + 3) * 16 + k4];
        a00 += x0.x * w0.x + x0.y * w1.x + x0.z * w2.x + x0.w * w3.x;
        a01 += x0.x * w0.y + x0.y * w1.y + x0.z * w2.y + x0.w * w3.y;
        a02 += x0.x * w0.z + x0.y * w1.z + x0.z * w2.z + x0.w * w3.z;
        a03 += x0.x * w0.w + x0.y * w1.w + x0.z * w2.w + x0.w * w3.w;
        a10 += x1.x * w0.x + x1.y * w1.x + x1.z * w2.x + x1.w * w3.x;
        a11 += x1.x * w0.y + x1.y * w1.y + x1.z * w2.y + x1.w * w3.y;
        a12 += x1.x * w0.z + x1.y * w1.z + x1.z * w2.z + x1.w * w3.z;
        a13 += x1.x * w0.w + x1.y * w1.w + x1.z * w2.w + x1.w * w3.w;
        a20 += x2.x * w0.x + x2.y * w1.x + x2.z * w2.x + x2.w * w3.x;
        a21 += x2.x * w0.y + x2.y * w1.y + x2.z * w2.y + x2.w * w3.y;
        a22 += x2.x * w0.z + x2.y * w1.z + x2.z * w2.z + x2.w * w3.z;
        a23 += x2.x * w0.w + x2.y * w1.w + x2.z * w2.w + x2.w * w3.w;
        a30 += x3.x * w0.x + x3.y * w1.x + x3.z * w2.x + x3.w * w3.x;
        a31 += x3.x * w0.y + x3.y * w1.y + x3.z * w2.y + x3.w * w3.y;
        a32 += x3.x * w0.z + x3.y * w1.z + x3.z * w2.z + x3.w * w3.z;
        a33 += x3.x * w0.w + x3.y * w1.w + x3.z * w2.w + x3.w * w3.w;
    }
    int vb = blockIdx.x * 64 + rg * 4;
    int v;
    float s;
    unsigned long long u;
    v = vb + 0;
    if (v < n) {
        s = scale[v];
        u  = (unsigned long long)(((unsigned int)f32_to_bf16(s * a01) << 16) | (unsigned int)f32_to_bf16(s * a00));
        u |= (unsigned long long)(((unsigned int)f32_to_bf16(s * a03) << 16) | (unsigned int)f32_to_bf16(s * a02)) << 32;
        C[(long)v * 16 + cg] = u;
    }
    v = vb + 1;
    if (v < n) {
        s = scale[v];
        u  = (unsigned long long)(((unsigned int)f32_to_bf16(s * a11) << 16) | (unsigned int)f32_to_bf16(s * a10));
        u |= (unsigned long long)(((unsigned int)f32_to_bf16(s * a13) << 16) | (unsigned int)f32_to_bf16(s * a12)) << 32;
        C[(long)v * 16 + cg] = u;
    }
    v = vb + 2;
    if (v < n) {
        s = scale[v];
        u  = (unsigned long long)(((unsigned int)f32_to_bf16(s * a21) << 16) | (unsigned int)f32_to_bf16(s * a20));
        u |= (unsigned long long)(((unsigned int)f32_to_bf16(s * a23) << 16) | (unsigned int)f32_to_bf16(s * a22)) << 32;
        C[(long)v * 16 + cg] = u;
    }
    v = vb + 3;
    if (v < n) {
        s = scale[v];
        u  = (unsigned long long)(((unsigned int)f32_to_bf16(s * a31) << 16) | (unsigned int)f32_to_bf16(s * a30));
        u |= (unsigned long long)(((unsigned int)f32_to_bf16(s * a33) << 16) | (unsigned int)f32_to_bf16(s * a32)) << 32;
        C[(long)v * 16 + cg] = u;
    }
}

// ---- gather stream v10 (R26): dwordx2 inside the proven stream skeleton.
// Lane (q=lane>>4, r=lane&15): 16 lanes x uint2 = one 128B row; q covers
// edges {q,4+q,8+q,12+q} of each 16-slot tier. Per tier: 4 uint2 gathers
// (addr = 1 add: j + r*8), prefetch next tier's 4 csr loads, consume.
// Node finish: fold s0..s3 over q (xor16+xor32); every lane selects s[q]
// = the sum for dim d=4r+q, so epilogues stay one scalar op per lane with
// contiguous d=0..63 coverage (no strided atomics -- R18 guard).
template <class F>
__device__ __forceinline__ void gather_stream(const char* __restrict__ xpb,
                                              const int* __restrict__ csr,
                                              int c0, int m0, int m1, int m2, int m3,
                                              int nv, int q, int r8, F fin) {
    int M = m0;
    if (nv > 1) M += m1;
    if (nv > 2) M += m2;
    if (nv > 3) M += m3;
    int c = c0 + q;
    int j0 = csr[c +  0];
    int j1 = csr[c +  4];
    int j2 = csr[c +  8];
    int j3 = csr[c + 12];
    float a0 = 0.f, a1 = 0.f, a2 = 0.f, a3 = 0.f;
    float b0 = 0.f, b1 = 0.f, b2 = 0.f, b3 = 0.f;
    int mrem = m0, cur = 0;
    for (int it = 0; it < M; ++it) {
        uint2 u0 = *(const uint2*)(xpb + (unsigned)(j0 + r8));  // 4 rows in flight
        uint2 u1 = *(const uint2*)(xpb + (unsigned)(j1 + r8));
        uint2 u2 = *(const uint2*)(xpb + (unsigned)(j2 + r8));
        uint2 u3 = *(const uint2*)(xpb + (unsigned)(j3 + r8));
        c += 16;                                   // prefetch next tier's j's
        int t0 = csr[c +  0];                      // (dead after last tier; csr
        int t1 = csr[c +  4];                      //  has tail slack)
        int t2 = csr[c +  8];
        int t3 = csr[c + 12];
        a0 += BLO(u0.x);  a1 += BHI(u0.x);  a2 += BLO(u0.y);  a3 += BHI(u0.y);
        b0 += BLO(u1.x);  b1 += BHI(u1.x);  b2 += BLO(u1.y);  b3 += BHI(u1.y);
        a0 += BLO(u2.x);  a1 += BHI(u2.x);  a2 += BLO(u2.y);  a3 += BHI(u2.y);
        b0 += BLO(u3.x);  b1 += BHI(u3.x);  b2 += BLO(u3.y);  b3 += BHI(u3.y);
        j0 = t0; j1 = t1; j2 = t2; j3 = t3;
        if (--mrem == 0) {                         // node done (wave-uniform)
            float s0 = a0 + b0, s1 = a1 + b1, s2 = a2 + b2, s3 = a3 + b3;
            s0 += __shfl_xor(s0, 16);  s0 += __shfl_xor(s0, 32);  // fold 4 q-groups
            s1 += __shfl_xor(s1, 16);  s1 += __shfl_xor(s1, 32);
            s2 += __shfl_xor(s2, 16);  s2 += __shfl_xor(s2, 32);
            s3 += __shfl_xor(s3, 16);  s3 += __shfl_xor(s3, 32);
            fin(cur, (q == 0) ? s0 : (q == 1) ? s1 : (q == 2) ? s2 : s3);
            a0 = a1 = a2 = a3 = 0.f;
            b0 = b1 = b2 = b3 = 0.f;
            ++cur;
            mrem = (cur == 1) ? m1 : ((cur == 2) ? m2 : m3);
        }
    }
}

// ---- R24 fused agg(layer1)+gemm(layer2): 64 nodes per 1024-thread block.
// Phase 1: 16 waves stream 4 nodes each, writing relu'd h rows into padded
// LDS tile (row stride 68 floats). Phase 2: gemm inner loop from LDS,
// scale by dinv, pack bf16 pairs -> xws2. Deletes the 51 MB h round-trip.
__global__ __launch_bounds__(1024) void agglin_k(
        const unsigned int* __restrict__ xp, const float* __restrict__ dinv,
        const int* __restrict__ start, const int* __restrict__ m16,
        const int* __restrict__ csr, const float* __restrict__ b1,
        const float* __restrict__ W2, unsigned long long* __restrict__ C, int n) {
    __shared__ float4 Wl4[64 * 16];       // 16 KB: W2[k][4c..4c+3]
    __shared__ float4 Hl4[64 * 17];       // 17.4 KB padded h tile
    int t = threadIdx.x;
    Wl4[t] = ((const float4*)W2)[t];      // 1024 float4 = full W2
    if (blockIdx.x == 0 && t < 16) C[(long)n * 16 + t] = 0ULL;  // zero row N of xws2
    int node0 = blockIdx.x * 64;
    int w = t >> 6, lane = t & 63;
    int q = lane >> 4, r = lane & 15;
    int v0 = node0 + w * 4;
    float* Hs = (float*)Hl4;              // scalar view, row stride 68
    if (v0 < n) {
        int nv = min(4, n - v0);
        int4 ss = *(const int4*)&start[v0];
        int4 mm = *(const int4*)&m16[v0];
        float4 dv = *(const float4*)&dinv[v0];
        int d = 4 * r + q;
        float b = b1[d];
        float* hrow = Hs + (w * 4) * 68 + d;
        gather_stream((const char*)xp, csr, ss.x, mm.x, mm.y, mm.z, mm.w, nv, q, r << 3,
            [&](int cur, float sum) {
                float dvv = (cur == 0) ? dv.x : (cur == 1) ? dv.y : (cur == 2) ? dv.z : dv.w;
                hrow[cur * 68] = fmaxf(fmaf(sum, dvv, b), 0.f);
            });
    }
    __syncthreads();
    // phase 2: thread -> row rg = t>>4 (0..63), colgroup cg = t&15
    int rg = t >> 4, cg = t & 15;
    int v = node0 + rg;
    if (v >= n) return;                   // after the only barrier: safe
    float a0 = 0.f, a1 = 0.f, a2 = 0.f, a3 = 0.f;
#pragma unroll 4
    for (int k4 = 0; k4 < 16; ++k4) {
        float4 w0 = Wl4[(4 * k4 + 0) * 16 + cg];
        float4 w1 = Wl4[(4 * k4 + 1) * 16 + cg];
        float4 w2 = Wl4[(4 * k4 + 2) * 16 + cg];
        float4 w3 = Wl4[(4 * k4 + 3) * 16 + cg];
        float4 x  = Hl4[rg * 17 + k4];
        a0 += x.x * w0.x + x.y * w1.x + x.z * w2.x + x.w * w3.x;
        a1 += x.x * w0.y + x.y * w1.y + x.z * w2.y + x.w * w3.y;
        a2 += x.x * w0.z + x.y * w1.z + x.z * w2.z + x.w * w3.z;
        a3 += x.x * w0.w + x.y * w1.w + x.z * w2.w + x.w * w3.w;
    }
    float s = dinv[v];
    unsigned long long u;
    u  = (unsigned long long)(((unsigned int)f32_to_bf16(s * a1) << 16) | (unsigned int)f32_to_bf16(s * a0));
    u |= (unsigned long long)(((unsigned int)f32_to_bf16(s * a3) << 16) | (unsigned int)f32_to_bf16(s * a2)) << 32;
    C[(long)v * 16 + cg] = u;
}

// ---- aggpool: 4 nodes/wave stream, 32x replicated pooled accumulator ----
__global__ void aggpool_k(const unsigned int* __restrict__ xp, const float* __restrict__ dinv,
                          const int* __restrict__ start, const int* __restrict__ m16,
                          const int* __restrict__ csr, const float* __restrict__ b2,
                          const int* __restrict__ batch, float* __restrict__ pooledR, int n) {
    int t = threadIdx.x;
    int lane = t & 63;
    int q = lane >> 4, r = lane & 15;
    int wid = blockIdx.x * 4 + (t >> 6);
    int v0 = wid * 4;
    if (v0 >= n) return;
    int nv = min(4, n - v0);
    int4 ss = *(const int4*)&start[v0];
    int4 mm = *(const int4*)&m16[v0];
    float4 dv = *(const float4*)&dinv[v0];
    int4 bt = *(const int4*)&batch[v0];
    int d = 4 * r + q;
    float bias = b2[d];
    long rbase = (long)(wid & (NREP - 1)) * (NGRAPH * NDIM);   // replica slice
    int gcur = -1;
    float acc = 0.f;
    gather_stream((const char*)xp, csr, ss.x, mm.x, mm.y, mm.z, mm.w, nv, q, r << 3,
        [&](int cur, float sum) {
            int g = (cur == 0) ? bt.x : (cur == 1) ? bt.y : (cur == 2) ? bt.z : bt.w;
            float dvv = (cur == 0) ? dv.x : (cur == 1) ? dv.y : (cur == 2) ? dv.z : dv.w;
            if (g != gcur) {
                if (gcur >= 0) atomicAdd(&pooledR[rbase + gcur * NDIM + d], acc);
                gcur = g;
                acc = 0.f;
            }
            acc += fmaxf(fmaf(sum, dvv, bias), 0.f);
        });
    if (gcur >= 0) atomicAdd(&pooledR[rbase + gcur * NDIM + d], acc);
}

// ---- fold the 32 pooled replicas (parallel, ~3 us) ----
__global__ void reduce_k(const float* __restrict__ pooledR, float* __restrict__ pooled) {
    int t = blockIdx.x * 256 + threadIdx.x;
    if (t >= NGRAPH * NDIM) return;
    float s = 0.f;
#pragma unroll
    for (int r = 0; r < NREP; ++r) s += pooledR[(long)r * (NGRAPH * NDIM) + t];
    pooled[t] = s;
}

// ---- head: out[g,c] = (pooled[g,:]/max(cnt,1)) @ Wlin + blin ----
__global__ void final_k(const float* __restrict__ pooled, const int* __restrict__ gstart,
                        const int* __restrict__ gend,
                        const float* __restrict__ Wlin, const float* __restrict__ blin,
                        float* __restrict__ out, int nclass) {
    int t = blockIdx.x * blockDim.x + threadIdx.x;
    if (t >= NGRAPH * nclass) return;
    int g = t / nclass, c = t % nclass;
    float cnt = (float)(gend[g] - gstart[g]);
    float inv = 1.f / fmaxf(cnt, 1.f);
    float acc = 0.f;
    for (int j = 0; j < NDIM; ++j) acc += pooled[g * NDIM + j] * Wlin[j * nclass + c];
    out[t] = acc * inv + blin[c];
}

extern "C" void kernel_launch(void* const* d_in, const int* in_sizes, int n_in,
                              void* d_out, int out_size, void* d_ws, size_t ws_size,
                              hipStream_t stream) {
    const float* x     = (const float*)d_in[0];
    const int*   ei    = (const int*)d_in[1];
    const int*   batch = (const int*)d_in[2];
    const float* W1    = (const float*)d_in[3];
    const float* b1    = (const float*)d_in[4];
    const float* W2    = (const float*)d_in[5];
    const float* b2    = (const float*)d_in[6];
    const float* Wlin  = (const float*)d_in[7];
    const float* blin  = (const float*)d_in[8];
    float* out = (float*)d_out;

    const int N = in_sizes[0] / NDIM;        // 100000
    const int E = in_sizes[1] / 2;           // 1600000
    const int NCLASS = in_sizes[7] / NDIM;   // 10
    const int* src = ei;
    const int* dst = ei + E;
    const int NB   = (N + BNODES - 1) >> BSHIFT;        // 782 buckets (<=1024)
    const int NBLK = (E + ECHUNK - 1) / ECHUNK;         // 782 edge blocks (<=1024)

    // ---- workspace carve-out (each 256B-aligned) ----
    size_t o = 0;
    char* wsp = (char*)d_ws;
    auto take = [&](size_t nbytes) -> void* {
        void* p = (void*)(wsp + o);
        o += (nbytes + 255) & ~(size_t)255;
        return p;
    };
    int*   gstart    = (int*)take(NGRAPH * 4);
    int*   gend      = (int*)take(NGRAPH * 4);
    float* pooledR   = (float*)take((size_t)NREP * NGRAPH * NDIM * 4);   // 512 KB
    float* pooled    = (float*)take(NGRAPH * NDIM * 4);
    int*   cntmat   = (int*)take((size_t)NBLK * NB * 4);
    int*   basemat  = (int*)take((size_t)NBLK * NB * 4);
    int*   bucketTot   = (int*)take((size_t)NB * 4);
    int*   bucketStart = (int*)take((size_t)(NB + 1) * 4);
    float* dinv  = (float*)take((size_t)N * 4);
    int*   start = (int*)take((size_t)(N + 1) * 4);
    int*   m16   = (int*)take((size_t)N * 4);
    int*   csr   = (int*)take(((size_t)E + (size_t)NB * PADSLOT + 256) * 4);  // padded CSR
    unsigned int* xws   = (unsigned int*)take((size_t)(N + 1) * NDIM * 2);  // layer-1 bf16 + zero row N
    unsigned int* xws2  = (unsigned int*)take((size_t)(N + 1) * NDIM * 2);  // layer-2 bf16 + zero row N
    unsigned int* ebuf  = (unsigned int*)take((size_t)E * 4);
    (void)ws_size;

    int rbl = (N + 15) / 16;                  // aggpool: 4 waves x 4 nodes per block
    int gbl = (N + 63) / 64;                  // 64 rows per block (gemm / agglin)

    // CSR build (deterministic two-pass binning, zero global atomics)
    bincnt_k<<<NBLK, 256, (size_t)NB * 4, stream>>>(dst, cntmat, E, NB);
    colscan_k<<<NB, 1024, 0, stream>>>(cntmat, basemat, bucketTot, pooledR, NBLK, NB);
    bscan_k<<<1, 1024, 0, stream>>>(bucketTot, bucketStart, start, gstart, gend, NB, N, E);
    bscatter_k<<<NBLK, 256, (size_t)NB * 4, stream>>>(src, dst, bucketStart, basemat, ebuf, E, NB);
    fill2_k<<<NB, 256, 0, stream>>>(ebuf, bucketStart, batch, dinv, start, m16, csr, gstart, gend, N);

    // layer 1 dense
    gemm_k<<<gbl, 256, 0, stream>>>(x, W1, dinv, (unsigned long long*)xws, N);
    // fused layer-1 aggregation + layer-2 dense (LDS handoff)
    agglin_k<<<gbl, 1024, 0, stream>>>(xws, dinv, start, m16, csr, b1, W2,
                                       (unsigned long long*)xws2, N);
    // fused layer-2 aggregation + replicated register mean-pool
    aggpool_k<<<rbl, 256, 0, stream>>>(xws2, dinv, start, m16, csr, b2, batch, pooledR, N);
    reduce_k<<<(NGRAPH * NDIM + 255) / 256, 256, 0, stream>>>(pooledR, pooled);
    // head
    final_k<<<(NGRAPH * NCLASS + 255) / 256, 256, 0, stream>>>(pooled, gstart, gend, Wlin, blin, out, NCLASS);
}

// Round 10
// 242.492 us; speedup vs baseline: 1.0392x; 1.0392x over previous
//
#include <hip/hip_runtime.h>
#include <hip/hip_bf16.h>

// GCN: h1 = relu(Â (x W1) + b1); h2 = relu(Â (h1 W2) + b2);
// out = mean_pool(h2, batch) @ Wlin + blin,  Â = D^-1/2 (A+I) D^-1/2
//
// R5/R6: bucketed CSR build, deterministic two-pass, zero global atomics.
// R8/R9 LESSON: sub-dword / strided per-lane global stores+atomics defeat
//     L2 write-merge. R12: multi-node unroll spills. R14: atomic chains.
// R15/R16: replicated pooled accumulators (chunk=4, 32 replicas).
// R17: 16-edge tier, 8 row-gathers in flight per half-wave. 280 us.
// R18 LESSON: branchy tails -> path-dependent vmcnt -> drain stalls.
// R19: CSR padded to 16-slot tiers (self-loop slot, zero-row pads). 276.6.
// R20: rotated-prefetch gather STREAM across node boundaries. -30 us.
// R20 LESSON: tiny-grid kernels must never own bulk reductions (110 us).
// R21: separate reduce_k + cheap final_k. 250.8 us.
// R22 LESSON: _ord-0 cold dispatch misread; neutral.
// R23 LESSON: depth-2 (16 outstanding) REGRESSED -- queue saturated.
// R24: agglin_k fusion (agg L1 + gemm L2 via padded LDS tile). 247.7 us.
// R25: csr = byte offsets -> 1-add addressing. 244.2 us. BEST.
// R26 LESSON: dwordx2 (4 outstanding/wave) REGRESSED (+8) -- vmcnt queue
//     counts INSTRUCTIONS; 4 entries/wave undersubscribes the CU queue
//     and exposes latency. R23+R26 bracket the optimum: 8 outstanding
//     dword gathers per wave. R25 shape is structurally optimal.
// R27: pure revert to R25.

#define NDIM 64
#define NGRAPH 64
#define NREP 32
#define BSHIFT 7                      // 128 nodes per bucket
#define BNODES 128
#define PADSLOT (BNODES * 16)         // worst-case extra csr slots per bucket
#define ECHUNK 2048                   // edges per block in bincnt/bscatter
#define EPB (ECHUNK / 256)            // edges per thread (8)

#define BLO(u) __uint_as_float((u) << 16)
#define BHI(u) __uint_as_float((u) & 0xFFFF0000u)

__device__ __forceinline__ unsigned short f32_to_bf16(float f) {
    unsigned int u = __float_as_uint(f);
    unsigned int r = 0x7FFFu + ((u >> 16) & 1u);   // round-to-nearest-even
    return (unsigned short)((u + r) >> 16);
}

// ---- pass 1: per-(block,bucket) edge counts via LDS histogram ----
__global__ void bincnt_k(const int* __restrict__ dst, int* __restrict__ cntmat,
                         int e, int nb) {
    extern __shared__ int hist[];
    int t = threadIdx.x;
    for (int i = t; i < nb; i += 256) hist[i] = 0;
    __syncthreads();
    int base = blockIdx.x * ECHUNK + t;
#pragma unroll
    for (int k = 0; k < EPB; ++k) {
        int i = base + k * 256;
        if (i < e) atomicAdd(&hist[dst[i] >> BSHIFT], 1);   // LDS atomic
    }
    __syncthreads();
    long row = (long)blockIdx.x * nb;
    for (int i = t; i < nb; i += 256) cntmat[row + i] = hist[i];
}

// ---- pass 2: per-bucket exclusive scan across blocks (one block per bucket) ----
// 1024-thread scan (nblk up to 1024). Also zeroes pooledR.
__global__ void colscan_k(const int* __restrict__ cntmat, int* __restrict__ basemat,
                          int* __restrict__ bucketTot, float* __restrict__ pooledR,
                          int nblk, int nb) {
    __shared__ int s[1024];
    int b = blockIdx.x;
    int t = threadIdx.x;
    int z = b * 1024 + t;
    if (z < NREP * NGRAPH * NDIM) pooledR[z] = 0.f;
    int v = (t < nblk) ? cntmat[(long)t * nb + b] : 0;
    s[t] = v;
    __syncthreads();
    for (int off = 1; off < 1024; off <<= 1) {
        int tmp = (t >= off) ? s[t - off] : 0;
        __syncthreads();
        s[t] += tmp;
        __syncthreads();
    }
    if (t < nblk) basemat[(long)t * nb + b] = s[t] - v;   // exclusive within column
    if (t == 1023) bucketTot[b] = s[1023];
}

// ---- pass 3: exclusive scan of bucket totals (single block, nb<=1024) ----
// Also zeroes gstart/gend (empty-graph safety; fill2_k overwrites).
__global__ void bscan_k(const int* __restrict__ bucketTot, int* __restrict__ bucketStart,
                        int* __restrict__ start, int* __restrict__ gstart,
                        int* __restrict__ gend, int nb, int n, int e) {
    __shared__ int s[1024];
    int t = threadIdx.x;
    if (t < NGRAPH) { gstart[t] = 0; gend[t] = 0; }
    int v = (t < nb) ? bucketTot[t] : 0;
    s[t] = v;
    __syncthreads();
    for (int off = 1; off < 1024; off <<= 1) {
        int tmp = (t >= off) ? s[t - off] : 0;
        __syncthreads();
        s[t] += tmp;
        __syncthreads();
    }
    if (t < nb) bucketStart[t + 1] = s[t];
    if (t == 0) { bucketStart[0] = 0; start[n] = e; }   // sentinel (unused by gather)
}

// ---- pass 4: scatter packed (dst_local<<25 | src) via block-private LDS cursors ----
__global__ void bscatter_k(const int* __restrict__ src, const int* __restrict__ dst,
                           const int* __restrict__ bucketStart,
                           const int* __restrict__ basemat,
                           unsigned int* __restrict__ ebuf, int e, int nb) {
    extern __shared__ int cur[];
    int t = threadIdx.x;
    long row = (long)blockIdx.x * nb;
    for (int i = t; i < nb; i += 256) cur[i] = bucketStart[i] + basemat[row + i];
    __syncthreads();
    int base = blockIdx.x * ECHUNK + t;
#pragma unroll
    for (int k = 0; k < EPB; ++k) {
        int i = base + k * 256;
        if (i < e) {
            int d = dst[i];
            int b = d >> BSHIFT;
            int pos = atomicAdd(&cur[b], 1);               // LDS atomic, block-private
            ebuf[pos] = ((unsigned)(d & (BNODES - 1)) << 25) | (unsigned)src[i];
        }
    }
}

// ---- pass 5: one block per bucket -> padded dst-ordered CSR slice, dinv, ranges ----
// Per-node slots = round_up(in_deg + 1(self), 16); bucket b's padded region
// starts at bucketStart[b] + b*PADSLOT. Pad slots point at zero row N.
// csr entries are BYTE offsets (src_id << 7) into the bf16 row table (R25).
__global__ void fill2_k(const unsigned int* __restrict__ ebuf,
                        const int* __restrict__ bucketStart,
                        const int* __restrict__ batch, float* __restrict__ dinv,
                        int* __restrict__ start, int* __restrict__ m16,
                        int* __restrict__ csr,
                        int* __restrict__ gstart, int* __restrict__ gend, int n) {
    __shared__ int scnt[BNODES], sincl[BNODES], scur[BNODES];
    int t = threadIdx.x;
    int b = blockIdx.x;
    int node0 = b << BSHIFT;
    int nNodes = min(BNODES, n - node0);
    if (t < BNODES) scnt[t] = 0;
    int e0 = bucketStart[b], e1 = bucketStart[b + 1];
    __syncthreads();
    for (int i = e0 + t; i < e1; i += 256)
        atomicAdd(&scnt[ebuf[i] >> 25], 1);
    __syncthreads();
    int val = (t < BNODES) ? scnt[t] : 0;
    int slots = (t < nNodes) ? ((val + 16) & ~15) : 0;   // real + self, padded to 16
    if (t < BNODES) sincl[t] = slots;
    __syncthreads();
    for (int off = 1; off < BNODES; off <<= 1) {
        int tmp = (t >= off && t < BNODES) ? sincl[t - off] : 0;
        __syncthreads();
        if (t < BNODES) sincl[t] += tmp;
        __syncthreads();
    }
    if (t < nNodes) {
        int v = node0 + t;
        int st = e0 + b * PADSLOT + sincl[t] - slots;   // exclusive scan, padded base
        start[v] = st;
        m16[v] = slots >> 4;                            // 16-edge tiers per node
        scur[t] = st;
        dinv[v] = rsqrtf((float)(val + 1));
        csr[st + val] = v << 7;                         // self-loop slot (byte off)
        for (int k2 = val + 1; k2 < slots; ++k2) csr[st + k2] = n << 7;  // zero-row pads
        int g = batch[v];                 // sorted-batch boundary detection
        if (v == 0 || batch[v - 1] != g) gstart[g] = v;
        if (v == n - 1 || batch[v + 1] != g) gend[g] = v + 1;
    }
    __syncthreads();
    for (int i = e0 + t; i < e1; i += 256) {
        unsigned rec = ebuf[i];
        int pos = atomicAdd(&scur[rec >> 25], 1);
        csr[pos] = (int)((rec & 0x1FFFFFFu) << 7);   // byte offset of src row
    }
}

// ---- dense GEMM v4  C[n,64](bf16 pairs) = scale[row] * (A[n,64] @ W[64,64]) ----
// Block 0 also zeroes dummy row N (replaces a memset dispatch).
__global__ void gemm_k(const float* __restrict__ A, const float* __restrict__ W,
                       const float* __restrict__ scale,
                       unsigned long long* __restrict__ C, int n) {
    __shared__ float4 Wl4[64 * 16];   // 16 KB: W[k][4c..4c+3]
    __shared__ float4 Xl4[64 * 16];   // 16 KB: X[r][4k..4k+3]
    int t = threadIdx.x;
    if (blockIdx.x == 0 && t < 16) C[(long)n * 16 + t] = 0ULL;   // zero row N
    const float4* W4 = (const float4*)W;
#pragma unroll
    for (int i = 0; i < 4; ++i) Wl4[t + 256 * i] = W4[t + 256 * i];
    const float4* A4 = (const float4*)A;
    long fbase = (long)blockIdx.x * 1024;
    long fmax  = (long)n * 16;
#pragma unroll
    for (int i = 0; i < 4; ++i) {
        long f = fbase + t + 256 * i;
        float4 v;
        if (f < fmax) v = A4[f];
        else { v.x = 0.f; v.y = 0.f; v.z = 0.f; v.w = 0.f; }
        Xl4[t + 256 * i] = v;
    }
    __syncthreads();
    int rg = t >> 4, cg = t & 15;
    float a00 = 0.f, a01 = 0.f, a02 = 0.f, a03 = 0.f;
    float a10 = 0.f, a11 = 0.f, a12 = 0.f, a13 = 0.f;
    float a20 = 0.f, a21 = 0.f, a22 = 0.f, a23 = 0.f;
    float a30 = 0.f, a31 = 0.f, a32 = 0.f, a33 = 0.f;
#pragma unroll 4
    for (int k4 = 0; k4 < 16; ++k4) {
        float4 w0 = Wl4[(4 * k4 + 0) * 16 + cg];
        float4 w1 = Wl4[(4 * k4 + 1) * 16 + cg];
        float4 w2 = Wl4[(4 * k4 + 2) * 16 + cg];
        float4 w3 = Wl4[(4 * k4 + 3) * 16 + cg];
        float4 x0 = Xl4[(4 * rg + 0) * 16 + k4];
        float4 x1 = Xl4[(4 * rg + 1) * 16 + k4];
        float4 x2 = Xl4[(4 * rg + 2) * 16 + k4];
        float4 x3 = Xl4[(4 * rg + 3) * 16 + k4];
        a00 += x0.x * w0.x + x0.y * w1.x + x0.z * w2.x + x0.w * w3.x;
        a01 += x0.x * w0.y + x0.y * w1.y + x0.z * w2.y + x0.w * w3.y;
        a02 += x0.x * w0.z + x0.y * w1.z + x0.z * w2.z + x0.w * w3.z;
        a03 += x0.x * w0.w + x0.y * w1.w + x0.z * w2.w + x0.w * w3.w;
        a10 += x1.x * w0.x + x1.y * w1.x + x1.z * w2.x + x1.w * w3.x;
        a11 += x1.x * w0.y + x1.y * w1.y + x1.z * w2.y + x1.w * w3.y;
        a12 += x1.x * w0.z + x1.y * w1.z + x1.z * w2.z + x1.w * w3.z;
        a13 += x1.x * w0.w + x1.y * w1.w + x1.z * w2.w + x1.w * w3.w;
        a20 += x2.x * w0.x + x2.y * w1.x + x2.z * w2.x + x2.w * w3.x;
        a21 += x2.x * w0.y + x2.y * w1.y + x2.z * w2.y + x2.w * w3.y;
        a22 += x2.x * w0.z + x2.y * w1.z + x2.z * w2.z + x2.w * w3.z;
        a23 += x2.x * w0.w + x2.y * w1.w + x2.z * w2.w + x2.w * w3.w;
        a30 += x3.x * w0.x + x3.y * w1.x + x3.z * w2.x + x3.w * w3.x;
        a31 += x3.x * w0.y + x3.y * w1.y + x3.z * w2.y + x3.w * w3.y;
        a32 += x3.x * w0.z + x3.y * w1.z + x3.z * w2.z + x3.w * w3.z;
        a33 += x3.x * w0.w + x3.y * w1.w + x3.z * w2.w + x3.w * w3.w;
    }
    int vb = blockIdx.x * 64 + rg * 4;
    int v;
    float s;
    unsigned long long u;
    v = vb + 0;
    if (v < n) {
        s = scale[v];
        u  = (unsigned long long)(((unsigned int)f32_to_bf16(s * a01) << 16) | (unsigned int)f32_to_bf16(s * a00));
        u |= (unsigned long long)(((unsigned int)f32_to_bf16(s * a03) << 16) | (unsigned int)f32_to_bf16(s * a02)) << 32;
        C[(long)v * 16 + cg] = u;
    }
    v = vb + 1;
    if (v < n) {
        s = scale[v];
        u  = (unsigned long long)(((unsigned int)f32_to_bf16(s * a11) << 16) | (unsigned int)f32_to_bf16(s * a10));
        u |= (unsigned long long)(((unsigned int)f32_to_bf16(s * a13) << 16) | (unsigned int)f32_to_bf16(s * a12)) << 32;
        C[(long)v * 16 + cg] = u;
    }
    v = vb + 2;
    if (v < n) {
        s = scale[v];
        u  = (unsigned long long)(((unsigned int)f32_to_bf16(s * a21) << 16) | (unsigned int)f32_to_bf16(s * a20));
        u |= (unsigned long long)(((unsigned int)f32_to_bf16(s * a23) << 16) | (unsigned int)f32_to_bf16(s * a22)) << 32;
        C[(long)v * 16 + cg] = u;
    }
    v = vb + 3;
    if (v < n) {
        s = scale[v];
        u  = (unsigned long long)(((unsigned int)f32_to_bf16(s * a31) << 16) | (unsigned int)f32_to_bf16(s * a30));
        u |= (unsigned long long)(((unsigned int)f32_to_bf16(s * a33) << 16) | (unsigned int)f32_to_bf16(s * a32)) << 32;
        C[(long)v * 16 + cg] = u;
    }
}

// ---- gather stream v9 (R25, PROVEN BEST): depth-1 stream, csr holds BYTE
// offsets. Per tier: issue 8 xp gathers (addr = one 32-bit add j+p4),
// prefetch next tier's 8 csr loads, consume. Node finish = wave-uniform
// mrem==0 epilogue via functor. All loads unconditional, named scalars.
template <class F>
__device__ __forceinline__ void gather_stream(const char* __restrict__ xpb,
                                              const int* __restrict__ csr,
                                              int c0, int m0, int m1, int m2, int m3,
                                              int nv, int h, int p4, F fin) {
    int M = m0;
    if (nv > 1) M += m1;
    if (nv > 2) M += m2;
    if (nv > 3) M += m3;
    int c = c0 + h;
    int j0 = csr[c +  0];
    int j1 = csr[c +  2];
    int j2 = csr[c +  4];
    int j3 = csr[c +  6];
    int j4 = csr[c +  8];
    int j5 = csr[c + 10];
    int j6 = csr[c + 12];
    int j7 = csr[c + 14];
    float l0 = 0.f, l1 = 0.f, l2 = 0.f, l3 = 0.f;
    float h0 = 0.f, h1 = 0.f, h2 = 0.f, h3 = 0.f;
    int mrem = m0, cur = 0;
    for (int it = 0; it < M; ++it) {
        unsigned int u0 = *(const unsigned*)(xpb + (unsigned)(j0 + p4));
        unsigned int u1 = *(const unsigned*)(xpb + (unsigned)(j1 + p4));
        unsigned int u2 = *(const unsigned*)(xpb + (unsigned)(j2 + p4));
        unsigned int u3 = *(const unsigned*)(xpb + (unsigned)(j3 + p4));
        unsigned int u4 = *(const unsigned*)(xpb + (unsigned)(j4 + p4));
        unsigned int u5 = *(const unsigned*)(xpb + (unsigned)(j5 + p4));
        unsigned int u6 = *(const unsigned*)(xpb + (unsigned)(j6 + p4));
        unsigned int u7 = *(const unsigned*)(xpb + (unsigned)(j7 + p4));
        c += 16;                                   // prefetch next tier's j's
        int t0 = csr[c +  0];                      // (dead after last tier; csr
        int t1 = csr[c +  2];                      //  has tail slack)
        int t2 = csr[c +  4];
        int t3 = csr[c +  6];
        int t4 = csr[c +  8];
        int t5 = csr[c + 10];
        int t6 = csr[c + 12];
        int t7 = csr[c + 14];
        l0 += BLO(u0);  h0 += BHI(u0);
        l1 += BLO(u1);  h1 += BHI(u1);
        l2 += BLO(u2);  h2 += BHI(u2);
        l3 += BLO(u3);  h3 += BHI(u3);
        l0 += BLO(u4);  h0 += BHI(u4);
        l1 += BLO(u5);  h1 += BHI(u5);
        l2 += BLO(u6);  h2 += BHI(u6);
        l3 += BLO(u7);  h3 += BHI(u7);
        j0 = t0; j1 = t1; j2 = t2; j3 = t3;
        j4 = t4; j5 = t5; j6 = t6; j7 = t7;
        if (--mrem == 0) {                         // node done (wave-uniform)
            float al = (l0 + l1) + (l2 + l3);
            float ah = (h0 + h1) + (h2 + h3);
            al += __shfl_xor(al, 32);              // merge the two half-waves
            ah += __shfl_xor(ah, 32);
            fin(cur, h ? ah : al);
            l0 = l1 = l2 = l3 = 0.f;
            h0 = h1 = h2 = h3 = 0.f;
            ++cur;
            mrem = (cur == 1) ? m1 : ((cur == 2) ? m2 : m3);
        }
    }
}

// ---- R24 fused agg(layer1)+gemm(layer2): 64 nodes per 1024-thread block.
// Phase 1: 16 waves stream 4 nodes each, writing relu'd h rows into padded
// LDS tile (row stride 68 floats; conflict-free scalar writes AND float4
// matmul reads). Phase 2: gemm inner loop from LDS, scale by dinv, pack
// bf16 pairs -> xws2. Deletes the 51 MB h round-trip.
__global__ __launch_bounds__(1024) void agglin_k(
        const unsigned int* __restrict__ xp, const float* __restrict__ dinv,
        const int* __restrict__ start, const int* __restrict__ m16,
        const int* __restrict__ csr, const float* __restrict__ b1,
        const float* __restrict__ W2, unsigned long long* __restrict__ C, int n) {
    __shared__ float4 Wl4[64 * 16];       // 16 KB: W2[k][4c..4c+3]
    __shared__ float4 Hl4[64 * 17];       // 17.4 KB padded h tile
    int t = threadIdx.x;
    Wl4[t] = ((const float4*)W2)[t];      // 1024 float4 = full W2
    if (blockIdx.x == 0 && t < 16) C[(long)n * 16 + t] = 0ULL;  // zero row N of xws2
    int node0 = blockIdx.x * 64;
    int w = t >> 6, lane = t & 63;
    int h = lane >> 5, p = lane & 31;
    int v0 = node0 + w * 4;
    float* Hs = (float*)Hl4;              // scalar view, row stride 68
    if (v0 < n) {
        int nv = min(4, n - v0);
        int4 ss = *(const int4*)&start[v0];
        int4 mm = *(const int4*)&m16[v0];
        float4 dv = *(const float4*)&dinv[v0];
        int d = 2 * p + h;
        float b = b1[d];
        float* hrow = Hs + (w * 4) * 68 + d;
        gather_stream((const char*)xp, csr, ss.x, mm.x, mm.y, mm.z, mm.w, nv, h, p << 2,
            [&](int cur, float sum) {
                float dvv = (cur == 0) ? dv.x : (cur == 1) ? dv.y : (cur == 2) ? dv.z : dv.w;
                hrow[cur * 68] = fmaxf(fmaf(sum, dvv, b), 0.f);
            });
    }
    __syncthreads();
    // phase 2: thread -> row rg = t>>4 (0..63), colgroup cg = t&15
    int rg = t >> 4, cg = t & 15;
    int v = node0 + rg;
    if (v >= n) return;                   // after the only barrier: safe
    float a0 = 0.f, a1 = 0.f, a2 = 0.f, a3 = 0.f;
#pragma unroll 4
    for (int k4 = 0; k4 < 16; ++k4) {
        float4 w0 = Wl4[(4 * k4 + 0) * 16 + cg];
        float4 w1 = Wl4[(4 * k4 + 1) * 16 + cg];
        float4 w2 = Wl4[(4 * k4 + 2) * 16 + cg];
        float4 w3 = Wl4[(4 * k4 + 3) * 16 + cg];
        float4 x  = Hl4[rg * 17 + k4];
        a0 += x.x * w0.x + x.y * w1.x + x.z * w2.x + x.w * w3.x;
        a1 += x.x * w0.y + x.y * w1.y + x.z * w2.y + x.w * w3.y;
        a2 += x.x * w0.z + x.y * w1.z + x.z * w2.z + x.w * w3.z;
        a3 += x.x * w0.w + x.y * w1.w + x.z * w2.w + x.w * w3.w;
    }
    float s = dinv[v];
    unsigned long long u;
    u  = (unsigned long long)(((unsigned int)f32_to_bf16(s * a1) << 16) | (unsigned int)f32_to_bf16(s * a0));
    u |= (unsigned long long)(((unsigned int)f32_to_bf16(s * a3) << 16) | (unsigned int)f32_to_bf16(s * a2)) << 32;
    C[(long)v * 16 + cg] = u;
}

// ---- aggpool: 4 nodes/wave stream, 32x replicated pooled accumulator ----
__global__ void aggpool_k(const unsigned int* __restrict__ xp, const float* __restrict__ dinv,
                          const int* __restrict__ start, const int* __restrict__ m16,
                          const int* __restrict__ csr, const float* __restrict__ b2,
                          const int* __restrict__ batch, float* __restrict__ pooledR, int n) {
    int t = threadIdx.x;
    int lane = t & 63;
    int h = lane >> 5, p = lane & 31;
    int wid = blockIdx.x * 4 + (t >> 6);
    int v0 = wid * 4;
    if (v0 >= n) return;
    int nv = min(4, n - v0);
    int4 ss = *(const int4*)&start[v0];
    int4 mm = *(const int4*)&m16[v0];
    float4 dv = *(const float4*)&dinv[v0];
    int4 bt = *(const int4*)&batch[v0];
    int d = 2 * p + h;
    float bias = b2[d];
    long rbase = (long)(wid & (NREP - 1)) * (NGRAPH * NDIM);   // replica slice
    int gcur = -1;
    float acc = 0.f;
    gather_stream((const char*)xp, csr, ss.x, mm.x, mm.y, mm.z, mm.w, nv, h, p << 2,
        [&](int cur, float sum) {
            int g = (cur == 0) ? bt.x : (cur == 1) ? bt.y : (cur == 2) ? bt.z : bt.w;
            float dvv = (cur == 0) ? dv.x : (cur == 1) ? dv.y : (cur == 2) ? dv.z : dv.w;
            if (g != gcur) {
                if (gcur >= 0) atomicAdd(&pooledR[rbase + gcur * NDIM + d], acc);
                gcur = g;
                acc = 0.f;
            }
            acc += fmaxf(fmaf(sum, dvv, bias), 0.f);
        });
    if (gcur >= 0) atomicAdd(&pooledR[rbase + gcur * NDIM + d], acc);
}

// ---- fold the 32 pooled replicas (parallel, ~3 us) ----
__global__ void reduce_k(const float* __restrict__ pooledR, float* __restrict__ pooled) {
    int t = blockIdx.x * 256 + threadIdx.x;
    if (t >= NGRAPH * NDIM) return;
    float s = 0.f;
#pragma unroll
    for (int r = 0; r < NREP; ++r) s += pooledR[(long)r * (NGRAPH * NDIM) + t];
    pooled[t] = s;
}

// ---- head: out[g,c] = (pooled[g,:]/max(cnt,1)) @ Wlin + blin ----
__global__ void final_k(const float* __restrict__ pooled, const int* __restrict__ gstart,
                        const int* __restrict__ gend,
                        const float* __restrict__ Wlin, const float* __restrict__ blin,
                        float* __restrict__ out, int nclass) {
    int t = blockIdx.x * blockDim.x + threadIdx.x;
    if (t >= NGRAPH * nclass) return;
    int g = t / nclass, c = t % nclass;
    float cnt = (float)(gend[g] - gstart[g]);
    float inv = 1.f / fmaxf(cnt, 1.f);
    float acc = 0.f;
    for (int j = 0; j < NDIM; ++j) acc += pooled[g * NDIM + j] * Wlin[j * nclass + c];
    out[t] = acc * inv + blin[c];
}

extern "C" void kernel_launch(void* const* d_in, const int* in_sizes, int n_in,
                              void* d_out, int out_size, void* d_ws, size_t ws_size,
                              hipStream_t stream) {
    const float* x     = (const float*)d_in[0];
    const int*   ei    = (const int*)d_in[1];
    const int*   batch = (const int*)d_in[2];
    const float* W1    = (const float*)d_in[3];
    const float* b1    = (const float*)d_in[4];
    const float* W2    = (const float*)d_in[5];
    const float* b2    = (const float*)d_in[6];
    const float* Wlin  = (const float*)d_in[7];
    const float* blin  = (const float*)d_in[8];
    float* out = (float*)d_out;

    const int N = in_sizes[0] / NDIM;        // 100000
    const int E = in_sizes[1] / 2;           // 1600000
    const int NCLASS = in_sizes[7] / NDIM;   // 10
    const int* src = ei;
    const int* dst = ei + E;
    const int NB   = (N + BNODES - 1) >> BSHIFT;        // 782 buckets (<=1024)
    const int NBLK = (E + ECHUNK - 1) / ECHUNK;         // 782 edge blocks (<=1024)

    // ---- workspace carve-out (each 256B-aligned) ----
    size_t o = 0;
    char* wsp = (char*)d_ws;
    auto take = [&](size_t nbytes) -> void* {
        void* p = (void*)(wsp + o);
        o += (nbytes + 255) & ~(size_t)255;
        return p;
    };
    int*   gstart    = (int*)take(NGRAPH * 4);
    int*   gend      = (int*)take(NGRAPH * 4);
    float* pooledR   = (float*)take((size_t)NREP * NGRAPH * NDIM * 4);   // 512 KB
    float* pooled    = (float*)take(NGRAPH * NDIM * 4);
    int*   cntmat   = (int*)take((size_t)NBLK * NB * 4);
    int*   basemat  = (int*)take((size_t)NBLK * NB * 4);
    int*   bucketTot   = (int*)take((size_t)NB * 4);
    int*   bucketStart = (int*)take((size_t)(NB + 1) * 4);
    float* dinv  = (float*)take((size_t)N * 4);
    int*   start = (int*)take((size_t)(N + 1) * 4);
    int*   m16   = (int*)take((size_t)N * 4);
    int*   csr   = (int*)take(((size_t)E + (size_t)NB * PADSLOT + 256) * 4);  // padded CSR
    unsigned int* xws   = (unsigned int*)take((size_t)(N + 1) * NDIM * 2);  // layer-1 bf16 + zero row N
    unsigned int* xws2  = (unsigned int*)take((size_t)(N + 1) * NDIM * 2);  // layer-2 bf16 + zero row N
    unsigned int* ebuf  = (unsigned int*)take((size_t)E * 4);
    (void)ws_size;

    int rbl = (N + 15) / 16;                  // aggpool: 4 waves x 4 nodes per block
    int gbl = (N + 63) / 64;                  // 64 rows per block (gemm / agglin)

    // CSR build (deterministic two-pass binning, zero global atomics)
    bincnt_k<<<NBLK, 256, (size_t)NB * 4, stream>>>(dst, cntmat, E, NB);
    colscan_k<<<NB, 1024, 0, stream>>>(cntmat, basemat, bucketTot, pooledR, NBLK, NB);
    bscan_k<<<1, 1024, 0, stream>>>(bucketTot, bucketStart, start, gstart, gend, NB, N, E);
    bscatter_k<<<NBLK, 256, (size_t)NB * 4, stream>>>(src, dst, bucketStart, basemat, ebuf, E, NB);
    fill2_k<<<NB, 256, 0, stream>>>(ebuf, bucketStart, batch, dinv, start, m16, csr, gstart, gend, N);

    // layer 1 dense
    gemm_k<<<gbl, 256, 0, stream>>>(x, W1, dinv, (unsigned long long*)xws, N);
    // fused layer-1 aggregation + layer-2 dense (LDS handoff)
    agglin_k<<<gbl, 1024, 0, stream>>>(xws, dinv, start, m16, csr, b1, W2,
                                       (unsigned long long*)xws2, N);
    // fused layer-2 aggregation + replicated register mean-pool
    aggpool_k<<<rbl, 256, 0, stream>>>(xws2, dinv, start, m16, csr, b2, batch, pooledR, N);
    reduce_k<<<(NGRAPH * NDIM + 255) / 256, 256, 0, stream>>>(pooledR, pooled);
    // head
    final_k<<<(NGRAPH * NCLASS + 255) / 256, 256, 0, stream>>>(pooled, gstart, gend, Wlin, blin, out, NCLASS);
}